// Round 1
// baseline (68.042 us; speedup 1.0000x reference)
//
#include <hip/hip_runtime.h>
#include <math.h>

// Analytic evaluation of the QNN circuit expectation values.
//
// Circuit: |psi> = C2 R2 C1 R1 E |0>, out(b,w) = <psi|Z_w|psi>
//   E  = prod_q RX(x[b,q]),  R1 = prod_q RX(W[0,q])  ->  merged: RX(t_q), t_q = x+W0
//   C  = CNOT(0,1), CNOT(1,2), ..., CNOT(15,0)  (applied in that order)
//   R2 = prod_q RX(W[1,q])
//
// Key identities (verified by hand vs explicit N=2 / N=3 simulation):
//  (a) C2^ Z_w C2 = Z_0...Z_w  (w>=1),  Z_1...Z_15  (w=0)
//  (b) RX(th)^ Z RX(th) = cos(th) Z + sin(th) Y  =: K  (full angle th!)
//  (c) C1|a> = |f(a)>, f: b_k = a_0^...^a_k (k>=1), b_0 = a_1^...^a_15
// Hence out(b,w) = <psi1| C1^ (⊗ M_q) C1 |psi1>, M_q = K_q if q in Q_w else I,
// psi1 = ⊗ (cos(t_q/2), -i sin(t_q/2)), which is a 4-state (p', p) prefix-XOR
// transfer-matrix chain over q=1..15 with a 4-branch periodic boundary at q=0.

#define NQ 16
#define BATCH 32

struct Cpx { float re, im; };
__device__ __forceinline__ Cpx cmul(Cpx a, Cpx b) {
    return { a.re * b.re - a.im * b.im, a.re * b.im + a.im * b.re };
}
__device__ __forceinline__ Cpx cadd(Cpx a, Cpx b) {
    return { a.re + b.re, a.im + b.im };
}

__global__ __launch_bounds__(64) void qnn_transfer_kernel(
        const float* __restrict__ x,     // (32,16)
        const float* __restrict__ wt,    // (2,16)
        float* __restrict__ out)         // (32,16)
{
    const int t = blockIdx.x * 64 + threadIdx.x;
    if (t >= BATCH * NQ) return;
    const int b = t >> 4;   // sample
    const int w = t & 15;   // measured wire

    // Per-wire scalars.
    // phi_q(0) = pc[q] (real), phi_q(1) = -i * ps[q]
    // K_q = [[kc, -i ks], [i ks, -kc]]
    float pc[NQ], ps[NQ], kc[NQ], ks[NQ];
    #pragma unroll
    for (int q = 0; q < NQ; ++q) {
        float t1 = x[b * NQ + q] + wt[q];        // x + weights[0][q]
        float th = wt[NQ + q];                   // weights[1][q]
        sincosf(0.5f * t1, &ps[q], &pc[q]);
        sincosf(th,        &ks[q], &kc[q]);
    }

    // Q_w: wires carrying K. w==0 -> {1..15}; w>=1 -> {0..w}.
    // Chain state index st = (p'<<1) | p. 4 boundary branches i = (a0'<<1)|a0,
    // carried as rows of V; V[i][st] complex.
    Cpx V[4][4];
    #pragma unroll
    for (int i = 0; i < 4; ++i) {
        const int al  = i & 1;         // a_0   (ket)
        const int alp = (i >> 1) & 1;  // a'_0  (bra)
        Cpx fk = al  ? Cpx{0.f, -ps[0]} : Cpx{pc[0], 0.f};
        Cpx fb = alp ? Cpx{0.f,  ps[0]} : Cpx{pc[0], 0.f};  // conj
        Cpx f = cmul(fk, fb);
        #pragma unroll
        for (int j = 0; j < 4; ++j) V[i][j] = (j == i) ? f : Cpx{0.f, 0.f};
    }

    // Transfer steps q = 1..15:
    // V_new[(r',r)] = [M_q]_{r',r} * sum_{p',p} conj(phi(r'^p')) phi(r^p) V[(p',p)]
    #pragma unroll
    for (int q = 1; q < NQ; ++q) {
        const bool inQ = (w == 0) ? true : (q <= w);
        const Cpx f0 = { pc[q], 0.f }, f1 = { 0.f, -ps[q] };
        const Cpx g0 = { pc[q], 0.f }, g1 = { 0.f,  ps[q] };   // conj(phi)
        Cpx M00, M01, M10, M11;
        if (inQ) { M00 = {kc[q], 0.f}; M01 = {0.f, -ks[q]};
                   M10 = {0.f, ks[q]}; M11 = {-kc[q], 0.f}; }
        else     { M00 = {1.f, 0.f};   M01 = {0.f, 0.f};
                   M10 = {0.f, 0.f};   M11 = {1.f, 0.f}; }
        #pragma unroll
        for (int i = 0; i < 4; ++i) {
            Cpx v00 = V[i][0], v01 = V[i][1], v10 = V[i][2], v11 = V[i][3];
            // ket sum over p: u[p'][r]
            Cpx u00 = cadd(cmul(f0, v00), cmul(f1, v01));
            Cpx u01 = cadd(cmul(f1, v00), cmul(f0, v01));
            Cpx u10 = cadd(cmul(f0, v10), cmul(f1, v11));
            Cpx u11 = cadd(cmul(f1, v10), cmul(f0, v11));
            // bra sum over p': z[r'][r]
            Cpx z00 = cadd(cmul(g0, u00), cmul(g1, u10));
            Cpx z01 = cadd(cmul(g0, u01), cmul(g1, u11));
            Cpx z10 = cadd(cmul(g1, u00), cmul(g0, u10));
            Cpx z11 = cadd(cmul(g1, u01), cmul(g0, u11));
            // elementwise matrix factor [M]_{r',r}
            V[i][0] = cmul(M00, z00);
            V[i][1] = cmul(M01, z01);
            V[i][2] = cmul(M10, z10);
            V[i][3] = cmul(M11, z11);
        }
    }

    // Periodic boundary at q = 0: b_0 = p_15 ^ a_0.
    // out = sum_{i=(a0',a0)} sum_{j=(b15',b15)} [M_0]_{b15'^a0', b15^a0} V[i][j]
    const bool q0in = (w >= 1);
    Cpx N00, N01, N10, N11;
    if (q0in) { N00 = {kc[0], 0.f}; N01 = {0.f, -ks[0]};
                N10 = {0.f, ks[0]}; N11 = {-kc[0], 0.f}; }
    else      { N00 = {1.f, 0.f};   N01 = {0.f, 0.f};
                N10 = {0.f, 0.f};   N11 = {1.f, 0.f}; }

    float acc = 0.f;
    #pragma unroll
    for (int i = 0; i < 4; ++i) {
        const int al  = i & 1;
        const int alp = (i >> 1) & 1;
        #pragma unroll
        for (int j = 0; j < 4; ++j) {
            const int be  = j & 1;
            const int bep = (j >> 1) & 1;
            const int row = bep ^ alp;
            const int col = be ^ al;
            Cpx m = (row == 0) ? (col == 0 ? N00 : N01)
                               : (col == 0 ? N10 : N11);
            acc += cmul(m, V[i][j]).re;   // result is real; imag cancels
        }
    }
    out[b * NQ + w] = acc;
}

extern "C" void kernel_launch(void* const* d_in, const int* in_sizes, int n_in,
                              void* d_out, int out_size, void* d_ws, size_t ws_size,
                              hipStream_t stream) {
    const float* x  = (const float*)d_in[0];   // (32,16) float32
    const float* wt = (const float*)d_in[1];   // (2,16)  float32
    float* out = (float*)d_out;                // (32,16) float32
    (void)in_sizes; (void)n_in; (void)out_size; (void)d_ws; (void)ws_size;

    qnn_transfer_kernel<<<(BATCH * NQ + 63) / 64, 64, 0, stream>>>(x, wt, out);
}

// Round 2
// 55.292 us; speedup vs baseline: 1.2306x; 1.2306x over previous
//
#include <hip/hip_runtime.h>
#include <math.h>

// Analytic evaluation of the QNN circuit expectation values (see R0 notes):
//
//   out(b,w) = <psi1| C1^ (⊗_q M_q) C1 |psi1>
//     psi1 = ⊗_q (cos(t_q/2), -i sin(t_q/2)),  t_q = x[b,q] + W[0,q]
//     M_q  = cos(th_q) Z + sin(th_q) Y  on wires Q_w (w=0 -> {1..15}, else {0..w}),
//            I elsewhere;  th_q = W[1,q]
//     C1   = ring of CNOTs = prefix-XOR basis permutation
//
// Evaluated as a 4-state (p',p) transfer-matrix chain over q=1..15 with a
// 4-branch periodic boundary (a0',a0) at q=0. This round: the 4 boundary
// branches are independent chains -> one thread each (tid = w*4 + branch),
// one block per sample b; trig shared via LDS; chain written in explicit
// real arithmetic (every complex factor is pure-real or pure-imaginary,
// so each complex product is 2 mults).

#define NQ 16
#define BATCH 32

__global__ __launch_bounds__(64) void qnn_transfer_kernel(
        const float* __restrict__ x,     // (32,16)
        const float* __restrict__ wt,    // (2,16)
        float* __restrict__ out)         // (32,16)
{
    const int b   = blockIdx.x;      // sample
    const int tid = threadIdx.x;     // w*4 + branch
    const int w   = tid >> 2;        // measured wire
    const int br  = tid & 3;         // boundary branch (alp<<1)|al
    const int al  = br & 1;          // a_0   (ket)
    const int alp = (br >> 1) & 1;   // a'_0  (bra)

    // Per-wire trig, computed once per block by 16 lanes.
    // phi_q(0)=pc[q] (real), phi_q(1)=-i*ps[q]; K_q=[[kc,-i ks],[i ks,-kc]]
    __shared__ float pc[NQ], ps[NQ], kc[NQ], ks[NQ];
    if (tid < NQ) {
        float t1 = x[b * NQ + tid] + wt[tid];   // x + weights[0][q]
        float th = wt[NQ + tid];                // weights[1][q]
        float sp, cp, sk, ck;
        sincosf(0.5f * t1, &sp, &cp);
        sincosf(th,        &sk, &ck);
        pc[tid] = cp; ps[tid] = sp; kc[tid] = ck; ks[tid] = sk;
    }
    __syncthreads();

    // Chain state V[(p'<<1)|p], complex, for this thread's boundary branch:
    // init V[br] = phi_0(al) * conj(phi_0(alp)), rest 0.
    //   br=0: c0^2 (re)   br=1: -i s0 c0   br=2: +i s0 c0   br=3: s0^2 (re)
    const float c0 = pc[0], s0 = ps[0];
    float v00r = (br == 0) ? c0 * c0 : 0.f, v00i = 0.f;
    float v01r = 0.f, v01i = (br == 1) ? -s0 * c0 : 0.f;
    float v10r = 0.f, v10i = (br == 2) ?  s0 * c0 : 0.f;
    float v11r = (br == 3) ? s0 * s0 : 0.f, v11i = 0.f;

    // Transfer steps q = 1..15:
    //   ket:  u_{p',r} = c*v_{p',r} + (-i s)*v_{p',r^1}
    //   bra:  z_{r',r} = c*u_{r',r} + (+i s)*u_{r'^1,r}
    //   gate: V_{r',r} = [M]_{r',r} * z_{r',r}
    //         M = [[a, -i e],[i e, d]], a=inQ?kc:1, e=inQ?ks:0, d=inQ?-kc:1
    #pragma unroll
    for (int q = 1; q < NQ; ++q) {
        const float c = pc[q], s = ps[q];
        const bool inQ = (w == 0) ? true : (q <= w);
        const float a = inQ ?  kc[q] : 1.f;
        const float e = inQ ?  ks[q] : 0.f;
        const float d = inQ ? -kc[q] : 1.f;

        // ket sum over p
        float u00r =  c * v00r + s * v01i, u00i =  c * v00i - s * v01r;
        float u01r =  s * v00i + c * v01r, u01i = -s * v00r + c * v01i;
        float u10r =  c * v10r + s * v11i, u10i =  c * v10i - s * v11r;
        float u11r =  s * v10i + c * v11r, u11i = -s * v10r + c * v11i;
        // bra sum over p' (conjugated phase: +i s)
        float z00r =  c * u00r - s * u10i, z00i =  c * u00i + s * u10r;
        float z01r =  c * u01r - s * u11i, z01i =  c * u01i + s * u11r;
        float z10r = -s * u00i + c * u10r, z10i =  s * u00r + c * u10i;
        float z11r = -s * u01i + c * u11r, z11i =  s * u01r + c * u11i;
        // elementwise gate factor
        v00r =  a * z00r;  v00i =  a * z00i;   // {a,0}  * z00
        v01r =  e * z01i;  v01i = -e * z01r;   // {0,-e} * z01
        v10r = -e * z10i;  v10i =  e * z10r;   // {0,+e} * z10
        v11r =  d * z11r;  v11i =  d * z11i;   // {d,0}  * z11
    }

    // Periodic boundary at q=0: b_0 = p_15 ^ a_0.
    // acc = sum_j Re( N_{bep^alp, be^al} * V[j] ), j=(bep<<1)|be
    //   N = [[A, -iB],[iB, D]]; contributions:
    //   (0,0): A*Vr  (0,1): B*Vi  (1,0): -B*Vi  (1,1): D*Vr
    const bool q0in = (w >= 1);
    const float A = q0in ?  kc[0] : 1.f;
    const float B = q0in ?  ks[0] : 0.f;
    const float D = q0in ? -kc[0] : 1.f;

    auto contrib = [&](int row, int col, float Vr, float Vi) -> float {
        return row ? (col ? D * Vr : -B * Vi)
                   : (col ? B * Vi :  A * Vr);
    };
    float acc = contrib(alp,     al,     v00r, v00i)   // j=0: be=0,bep=0
              + contrib(alp,     al ^ 1, v01r, v01i)   // j=1: be=1,bep=0
              + contrib(alp ^ 1, al,     v10r, v10i)   // j=2: be=0,bep=1
              + contrib(alp ^ 1, al ^ 1, v11r, v11i);  // j=3: be=1,bep=1

    // Sum the 4 boundary branches (lanes w*4+0..3, xor stays in-group).
    acc += __shfl_xor(acc, 1);
    acc += __shfl_xor(acc, 2);
    if (br == 0) out[b * NQ + w] = acc;
}

extern "C" void kernel_launch(void* const* d_in, const int* in_sizes, int n_in,
                              void* d_out, int out_size, void* d_ws, size_t ws_size,
                              hipStream_t stream) {
    const float* x  = (const float*)d_in[0];   // (32,16) float32
    const float* wt = (const float*)d_in[1];   // (2,16)  float32
    float* out = (float*)d_out;                // (32,16) float32
    (void)in_sizes; (void)n_in; (void)out_size; (void)d_ws; (void)ws_size;

    qnn_transfer_kernel<<<BATCH, 64, 0, stream>>>(x, wt, out);
}